// Round 1
// baseline (2880.799 us; speedup 1.0000x reference)
//
#include <hip/hip_runtime.h>
#include <math.h>

#define D_DIM 1024
#define H_DIM 4096
#define R_DIM 64
#define S_SP  4
#define NTOK  8192
#define CHUNK 1024   // H/S

// ---------------- K0: transpose W2 (D,H) -> W2T (H,D) ----------------
__global__ __launch_bounds__(256) void k_transpose(const float* __restrict__ W2,
                                                   float* __restrict__ W2T) {
  __shared__ float tile[64][65];
  const int hb = blockIdx.x * 64, db = blockIdx.y * 64;
  const int tx = threadIdx.x & 63, ty = threadIdx.x >> 6;
#pragma unroll
  for (int r = 0; r < 16; ++r) {
    const int d = ty * 16 + r;
    tile[tx][d] = W2[(size_t)(db + d) * H_DIM + hb + tx];
  }
  __syncthreads();
#pragma unroll
  for (int r = 0; r < 16; ++r) {
    const int h = ty * 16 + r;
    W2T[(size_t)(hb + h) * D_DIM + db + tx] = tile[h][tx];
  }
}

// ---------------- K1: ch = relu(x @ Wc1^T + bc1)  (8192x64, K=1024) ----
#define K1_TOK 16
__global__ __launch_bounds__(256) void k_ctrl(const float* __restrict__ x,
                                              const float* __restrict__ Wc1,
                                              const float* __restrict__ bc1,
                                              float* __restrict__ ch) {
  __shared__ float xs[K1_TOK * 64];
  const int tid = threadIdx.x;
  const int tok0 = blockIdx.x * K1_TOK;
  const int r = tid & 63;   // output column r (R=64)
  const int g = tid >> 6;   // token group 0..3 (4 tokens each)
  float acc[4] = {0.f, 0.f, 0.f, 0.f};
#pragma unroll 1
  for (int kt = 0; kt < D_DIM; kt += 64) {
    __syncthreads();
    {
      const int tk = tid >> 4, kk = (tid & 15) * 4;
      *(float4*)(xs + tk * 64 + kk) =
          *(const float4*)(x + (size_t)(tok0 + tk) * D_DIM + kt + kk);
    }
    __syncthreads();
    float4 w[16];
#pragma unroll
    for (int q = 0; q < 16; ++q)
      w[q] = *(const float4*)(Wc1 + (size_t)r * D_DIM + kt + q * 4);
#pragma unroll
    for (int t = 0; t < 4; ++t) {
      const float* cp = xs + (g * 4 + t) * 64;
      float a0 = 0.f, a1 = 0.f, a2 = 0.f, a3 = 0.f;
#pragma unroll
      for (int q = 0; q < 16; q += 4) {
        const float4 c0 = *(const float4*)(cp + (q + 0) * 4);
        const float4 c1 = *(const float4*)(cp + (q + 1) * 4);
        const float4 c2 = *(const float4*)(cp + (q + 2) * 4);
        const float4 c3 = *(const float4*)(cp + (q + 3) * 4);
        a0 = fmaf(c0.x, w[q+0].x, fmaf(c0.y, w[q+0].y, fmaf(c0.z, w[q+0].z, fmaf(c0.w, w[q+0].w, a0))));
        a1 = fmaf(c1.x, w[q+1].x, fmaf(c1.y, w[q+1].y, fmaf(c1.z, w[q+1].z, fmaf(c1.w, w[q+1].w, a1))));
        a2 = fmaf(c2.x, w[q+2].x, fmaf(c2.y, w[q+2].y, fmaf(c2.z, w[q+2].z, fmaf(c2.w, w[q+2].w, a2))));
        a3 = fmaf(c3.x, w[q+3].x, fmaf(c3.y, w[q+3].y, fmaf(c3.z, w[q+3].z, fmaf(c3.w, w[q+3].w, a3))));
      }
      acc[t] += (a0 + a1) + (a2 + a3);
    }
  }
#pragma unroll
  for (int t = 0; t < 4; ++t) {
    const float v = acc[t] + bc1[r];
    ch[(size_t)(tok0 + g * 4 + t) * R_DIM + r] = v > 0.f ? v : 0.f;
  }
}

// ------- K2: logits = ch @ Wc2^T + bc2 (+gumbel), per-chunk argmax ------
// grid = (NTOK/K2_TOK, S). Each thread owns one Wc2 row (in VGPRs) per hi,
// loops tokens with ch broadcast from LDS; bests kept in registers.
#define K2_TOK 16
__global__ __launch_bounds__(256) void k_gate(const float* __restrict__ ch,
                                              const float* __restrict__ Wc2,
                                              const float* __restrict__ bc2,
                                              const float* __restrict__ gumbel,
                                              int* __restrict__ idx) {
  __shared__ float chs[K2_TOK * 64];
  __shared__ float redv[4][K2_TOK];
  __shared__ int   redi[4][K2_TOK];
  const int tid = threadIdx.x;
  const int tok0 = blockIdx.x * K2_TOK;
  const int s = blockIdx.y;
  {
    const int tk = tid >> 4, kk = (tid & 15) * 4;
    *(float4*)(chs + tk * 64 + kk) =
        *(const float4*)(ch + (size_t)(tok0 + tk) * R_DIM + kk);
  }
  __syncthreads();
  float bv[K2_TOK];
  int   bi[K2_TOK];
#pragma unroll
  for (int t = 0; t < K2_TOK; ++t) { bv[t] = -INFINITY; bi[t] = 0; }
#pragma unroll 1
  for (int hi = 0; hi < 4; ++hi) {
    const int hloc = hi * 256 + tid;              // h within chunk, 0..1023
    const float* wrow = Wc2 + (size_t)(s * CHUNK + hloc) * R_DIM;
    float4 w[16];
#pragma unroll
    for (int q = 0; q < 16; ++q) w[q] = *(const float4*)(wrow + q * 4);
    const float bias = bc2[s * CHUNK + hloc];
    const float* gp = gumbel + ((size_t)tok0 * 4 + s) * CHUNK + hloc;
#pragma unroll
    for (int t = 0; t < K2_TOK; ++t) {
      const float* cp = chs + t * 64;
      const float gum = gp[(size_t)t * 4 * CHUNK];
      float a0 = 0.f, a1 = 0.f, a2 = 0.f, a3 = 0.f;
#pragma unroll
      for (int q = 0; q < 16; q += 4) {
        const float4 c0 = *(const float4*)(cp + (q + 0) * 4);
        const float4 c1 = *(const float4*)(cp + (q + 1) * 4);
        const float4 c2 = *(const float4*)(cp + (q + 2) * 4);
        const float4 c3 = *(const float4*)(cp + (q + 3) * 4);
        a0 = fmaf(c0.x, w[q+0].x, fmaf(c0.y, w[q+0].y, fmaf(c0.z, w[q+0].z, fmaf(c0.w, w[q+0].w, a0))));
        a1 = fmaf(c1.x, w[q+1].x, fmaf(c1.y, w[q+1].y, fmaf(c1.z, w[q+1].z, fmaf(c1.w, w[q+1].w, a1))));
        a2 = fmaf(c2.x, w[q+2].x, fmaf(c2.y, w[q+2].y, fmaf(c2.z, w[q+2].z, fmaf(c2.w, w[q+2].w, a2))));
        a3 = fmaf(c3.x, w[q+3].x, fmaf(c3.y, w[q+3].y, fmaf(c3.z, w[q+3].z, fmaf(c3.w, w[q+3].w, a3))));
      }
      const float val = (a0 + a1) + (a2 + a3) + bias + gum;
      if (val > bv[t] || (val == bv[t] && hloc < bi[t])) { bv[t] = val; bi[t] = hloc; }
    }
  }
  // argmax reduce: wave shuffle, then cross-wave via LDS
#pragma unroll
  for (int t = 0; t < K2_TOK; ++t) {
    float v = bv[t];
    int ii = bi[t];
#pragma unroll
    for (int o = 32; o > 0; o >>= 1) {
      const float ov = __shfl_down(v, o);
      const int   oi = __shfl_down(ii, o);
      if (ov > v || (ov == v && oi < ii)) { v = ov; ii = oi; }
    }
    if ((tid & 63) == 0) { redv[tid >> 6][t] = v; redi[tid >> 6][t] = ii; }
  }
  __syncthreads();
  if (tid < K2_TOK) {
    float v = redv[0][tid];
    int ii = redi[0][tid];
#pragma unroll
    for (int wv = 1; wv < 4; ++wv) {
      const float ov = redv[wv][tid];
      const int   oi = redi[wv][tid];
      if (ov > v || (ov == v && oi < ii)) { v = ov; ii = oi; }
    }
    idx[(size_t)(tok0 + tid) * S_SP + s] = s * CHUNK + ii;
  }
}

// ------- K3: per-token sparse FFN: 4 dots with W1 rows, combine W2T rows ---
__global__ __launch_bounds__(256) void k_ffn(const float* __restrict__ x,
                                             const float* __restrict__ W1,
                                             const float* __restrict__ b1,
                                             const float* __restrict__ W2T,
                                             const float* __restrict__ b2,
                                             const int* __restrict__ idx,
                                             float* __restrict__ out) {
  __shared__ float red[4][4];
  __shared__ float hv[4];
  const int token = blockIdx.x;
  const int tid = threadIdx.x;
  const int4 h4 = *(const int4*)(idx + (size_t)token * S_SP);
  const int h[4] = {h4.x, h4.y, h4.z, h4.w};
  const int d4 = tid * 4;
  const float4 xv = *(const float4*)(x + (size_t)token * D_DIM + d4);
  float p[4];
#pragma unroll
  for (int s2 = 0; s2 < 4; ++s2) {
    const float4 wv = *(const float4*)(W1 + (size_t)h[s2] * D_DIM + d4);
    p[s2] = xv.x * wv.x + xv.y * wv.y + xv.z * wv.z + xv.w * wv.w;
  }
#pragma unroll
  for (int s2 = 0; s2 < 4; ++s2) {
    float v = p[s2];
#pragma unroll
    for (int o = 32; o > 0; o >>= 1) v += __shfl_down(v, o);
    if ((tid & 63) == 0) red[tid >> 6][s2] = v;
  }
  __syncthreads();
  if (tid < 4) {
    const float tot = red[0][tid] + red[1][tid] + red[2][tid] + red[3][tid];
    const int hh = (tid == 0) ? h4.x : (tid == 1) ? h4.y : (tid == 2) ? h4.z : h4.w;
    const float v = tot + b1[hh];
    hv[tid] = v > 0.f ? v : 0.f;
  }
  __syncthreads();
  const float h0 = hv[0], h1 = hv[1], h2 = hv[2], h3 = hv[3];
  float4 o4 = *(const float4*)(b2 + d4);
  const float4 w0 = *(const float4*)(W2T + (size_t)h[0] * D_DIM + d4);
  const float4 w1 = *(const float4*)(W2T + (size_t)h[1] * D_DIM + d4);
  const float4 w2 = *(const float4*)(W2T + (size_t)h[2] * D_DIM + d4);
  const float4 w3 = *(const float4*)(W2T + (size_t)h[3] * D_DIM + d4);
  o4.x += h0 * w0.x + h1 * w1.x + h2 * w2.x + h3 * w3.x;
  o4.y += h0 * w0.y + h1 * w1.y + h2 * w2.y + h3 * w3.y;
  o4.z += h0 * w0.z + h1 * w1.z + h2 * w2.z + h3 * w3.z;
  o4.w += h0 * w0.w + h1 * w1.w + h2 * w2.w + h3 * w3.w;
  *(float4*)(out + (size_t)token * D_DIM + d4) = o4;
}

extern "C" void kernel_launch(void* const* d_in, const int* in_sizes, int n_in,
                              void* d_out, int out_size, void* d_ws, size_t ws_size,
                              hipStream_t stream) {
  const float* x      = (const float*)d_in[0];
  const float* W1     = (const float*)d_in[1];
  const float* b1     = (const float*)d_in[2];
  const float* W2     = (const float*)d_in[3];
  const float* b2     = (const float*)d_in[4];
  const float* Wc1    = (const float*)d_in[5];
  const float* bc1    = (const float*)d_in[6];
  const float* Wc2    = (const float*)d_in[7];
  const float* bc2    = (const float*)d_in[8];
  const float* gumbel = (const float*)d_in[9];
  float* out = (float*)d_out;

  char* ws = (char*)d_ws;
  float* W2T = (float*)ws;                                           // 16.78 MB
  float* ch  = (float*)(ws + (size_t)H_DIM * D_DIM * 4);             //  2.10 MB
  int*   idx = (int*)(ws + (size_t)H_DIM * D_DIM * 4
                         + (size_t)NTOK * R_DIM * 4);                //  0.13 MB

  hipLaunchKernelGGL(k_transpose, dim3(H_DIM / 64, D_DIM / 64), dim3(256), 0, stream,
                     W2, W2T);
  hipLaunchKernelGGL(k_ctrl, dim3(NTOK / K1_TOK), dim3(256), 0, stream,
                     x, Wc1, bc1, ch);
  hipLaunchKernelGGL(k_gate, dim3(NTOK / K2_TOK, S_SP), dim3(256), 0, stream,
                     ch, Wc2, bc2, gumbel, idx);
  hipLaunchKernelGGL(k_ffn, dim3(NTOK), dim3(256), 0, stream,
                     x, W1, b1, W2T, b2, idx, out);
}

// Round 2
// 2152.902 us; speedup vs baseline: 1.3381x; 1.3381x over previous
//
#include <hip/hip_runtime.h>
#include <math.h>

#define D_DIM 1024
#define H_DIM 4096
#define R_DIM 64
#define S_SP  4
#define NTOK  8192
#define CHUNK 1024   // H/S

// ---------------- K0: transpose W2 (D,H) -> W2T (H,D) ----------------
__global__ __launch_bounds__(256) void k_transpose(const float* __restrict__ W2,
                                                   float* __restrict__ W2T) {
  __shared__ float tile[64][65];
  const int hb = blockIdx.x * 64, db = blockIdx.y * 64;
  const int tx = threadIdx.x & 63, ty = threadIdx.x >> 6;
#pragma unroll
  for (int r = 0; r < 16; ++r) {
    const int d = ty * 16 + r;
    tile[tx][d] = W2[(size_t)(db + d) * H_DIM + hb + tx];
  }
  __syncthreads();
#pragma unroll
  for (int r = 0; r < 16; ++r) {
    const int h = ty * 16 + r;
    W2T[(size_t)(hb + h) * D_DIM + db + tx] = tile[h][tx];
  }
}

// ---------------- K1: ch = relu(x @ Wc1^T + bc1)  (8192x64, K=1024) ----
#define K1_TOK 16
__global__ __launch_bounds__(256) void k_ctrl(const float* __restrict__ x,
                                              const float* __restrict__ Wc1,
                                              const float* __restrict__ bc1,
                                              float* __restrict__ ch) {
  __shared__ float xs[K1_TOK * 64];
  const int tid = threadIdx.x;
  const int tok0 = blockIdx.x * K1_TOK;
  const int r = tid & 63;   // output column r (R=64)
  const int g = tid >> 6;   // token group 0..3 (4 tokens each)
  float acc[4] = {0.f, 0.f, 0.f, 0.f};
#pragma unroll 1
  for (int kt = 0; kt < D_DIM; kt += 64) {
    __syncthreads();
    {
      const int tk = tid >> 4, kk = (tid & 15) * 4;
      *(float4*)(xs + tk * 64 + kk) =
          *(const float4*)(x + (size_t)(tok0 + tk) * D_DIM + kt + kk);
    }
    __syncthreads();
    // 16-float chunks of the Wc1 row to keep register pressure low
#pragma unroll
    for (int kk = 0; kk < 4; ++kk) {
      const float4 w0 = *(const float4*)(Wc1 + (size_t)r * D_DIM + kt + kk * 16 + 0);
      const float4 w1 = *(const float4*)(Wc1 + (size_t)r * D_DIM + kt + kk * 16 + 4);
      const float4 w2 = *(const float4*)(Wc1 + (size_t)r * D_DIM + kt + kk * 16 + 8);
      const float4 w3 = *(const float4*)(Wc1 + (size_t)r * D_DIM + kt + kk * 16 + 12);
#pragma unroll
      for (int t = 0; t < 4; ++t) {
        const float* cp = xs + (g * 4 + t) * 64 + kk * 16;
        const float4 c0 = *(const float4*)(cp + 0);
        const float4 c1 = *(const float4*)(cp + 4);
        const float4 c2 = *(const float4*)(cp + 8);
        const float4 c3 = *(const float4*)(cp + 12);
        float a = acc[t];
        a = fmaf(c0.x, w0.x, a); a = fmaf(c0.y, w0.y, a);
        a = fmaf(c0.z, w0.z, a); a = fmaf(c0.w, w0.w, a);
        a = fmaf(c1.x, w1.x, a); a = fmaf(c1.y, w1.y, a);
        a = fmaf(c1.z, w1.z, a); a = fmaf(c1.w, w1.w, a);
        a = fmaf(c2.x, w2.x, a); a = fmaf(c2.y, w2.y, a);
        a = fmaf(c2.z, w2.z, a); a = fmaf(c2.w, w2.w, a);
        a = fmaf(c3.x, w3.x, a); a = fmaf(c3.y, w3.y, a);
        a = fmaf(c3.z, w3.z, a); a = fmaf(c3.w, w3.w, a);
        acc[t] = a;
      }
    }
  }
#pragma unroll
  for (int t = 0; t < 4; ++t) {
    const float v = acc[t] + bc1[r];
    ch[(size_t)(tok0 + g * 4 + t) * R_DIM + r] = v > 0.f ? v : 0.f;
  }
}

// ------- K2: logits = ch @ Wc2^T + bc2 (+gumbel), per-chunk argmax ------
// grid = (NTOK/K2_TOK, S). Thread owns h = hi*256+tid; persistent acc[16]
// (per-token partials); Wc2 row consumed in 16-float chunks (low VGPR).
#define K2_TOK 16
__global__ __launch_bounds__(256) void k_gate(const float* __restrict__ ch,
                                              const float* __restrict__ Wc2,
                                              const float* __restrict__ bc2,
                                              const float* __restrict__ gumbel,
                                              int* __restrict__ idx) {
  __shared__ float chs[K2_TOK * 64];
  __shared__ float redv[4][K2_TOK];
  __shared__ int   redi[4][K2_TOK];
  const int tid = threadIdx.x;
  const int tok0 = blockIdx.x * K2_TOK;
  const int s = blockIdx.y;
  {
    const int tk = tid >> 4, kk = (tid & 15) * 4;
    *(float4*)(chs + tk * 64 + kk) =
        *(const float4*)(ch + (size_t)(tok0 + tk) * R_DIM + kk);
  }
  __syncthreads();
  float bv[K2_TOK];
  int   bi[K2_TOK];
#pragma unroll
  for (int t = 0; t < K2_TOK; ++t) { bv[t] = -INFINITY; bi[t] = 0; }
#pragma unroll 1
  for (int hi = 0; hi < 4; ++hi) {
    const int hloc = hi * 256 + tid;              // h within chunk, 0..1023
    const float* wrow = Wc2 + (size_t)(s * CHUNK + hloc) * R_DIM;
    float acc[K2_TOK];
#pragma unroll
    for (int t = 0; t < K2_TOK; ++t) acc[t] = 0.f;
#pragma unroll
    for (int kk = 0; kk < 4; ++kk) {
      const float4 w0 = *(const float4*)(wrow + kk * 16 + 0);
      const float4 w1 = *(const float4*)(wrow + kk * 16 + 4);
      const float4 w2 = *(const float4*)(wrow + kk * 16 + 8);
      const float4 w3 = *(const float4*)(wrow + kk * 16 + 12);
#pragma unroll
      for (int t = 0; t < K2_TOK; ++t) {
        const float* cp = chs + t * 64 + kk * 16;
        const float4 c0 = *(const float4*)(cp + 0);
        const float4 c1 = *(const float4*)(cp + 4);
        const float4 c2 = *(const float4*)(cp + 8);
        const float4 c3 = *(const float4*)(cp + 12);
        float a = acc[t];
        a = fmaf(c0.x, w0.x, a); a = fmaf(c0.y, w0.y, a);
        a = fmaf(c0.z, w0.z, a); a = fmaf(c0.w, w0.w, a);
        a = fmaf(c1.x, w1.x, a); a = fmaf(c1.y, w1.y, a);
        a = fmaf(c1.z, w1.z, a); a = fmaf(c1.w, w1.w, a);
        a = fmaf(c2.x, w2.x, a); a = fmaf(c2.y, w2.y, a);
        a = fmaf(c2.z, w2.z, a); a = fmaf(c2.w, w2.w, a);
        a = fmaf(c3.x, w3.x, a); a = fmaf(c3.y, w3.y, a);
        a = fmaf(c3.z, w3.z, a); a = fmaf(c3.w, w3.w, a);
        acc[t] = a;
      }
    }
    const float bias = bc2[s * CHUNK + hloc];
    const float* gp = gumbel + ((size_t)tok0 * 4 + s) * CHUNK + hloc;
#pragma unroll
    for (int t = 0; t < K2_TOK; ++t) {
      const float val = acc[t] + bias + gp[(size_t)t * 4 * CHUNK];
      if (val > bv[t] || (val == bv[t] && hloc < bi[t])) { bv[t] = val; bi[t] = hloc; }
    }
  }
  // argmax reduce: wave shuffle, then cross-wave via LDS
#pragma unroll
  for (int t = 0; t < K2_TOK; ++t) {
    float v = bv[t];
    int ii = bi[t];
#pragma unroll
    for (int o = 32; o > 0; o >>= 1) {
      const float ov = __shfl_down(v, o);
      const int   oi = __shfl_down(ii, o);
      if (ov > v || (ov == v && oi < ii)) { v = ov; ii = oi; }
    }
    if ((tid & 63) == 0) { redv[tid >> 6][t] = v; redi[tid >> 6][t] = ii; }
  }
  __syncthreads();
  if (tid < K2_TOK) {
    float v = redv[0][tid];
    int ii = redi[0][tid];
#pragma unroll
    for (int wv = 1; wv < 4; ++wv) {
      const float ov = redv[wv][tid];
      const int   oi = redi[wv][tid];
      if (ov > v || (ov == v && oi < ii)) { v = ov; ii = oi; }
    }
    idx[(size_t)(tok0 + tid) * S_SP + s] = s * CHUNK + ii;
  }
}

// ------- K3: per-token sparse FFN: 4 dots with W1 rows, combine W2T rows ---
__global__ __launch_bounds__(256) void k_ffn(const float* __restrict__ x,
                                             const float* __restrict__ W1,
                                             const float* __restrict__ b1,
                                             const float* __restrict__ W2T,
                                             const float* __restrict__ b2,
                                             const int* __restrict__ idx,
                                             float* __restrict__ out) {
  __shared__ float red[4][4];
  __shared__ float hv[4];
  const int token = blockIdx.x;
  const int tid = threadIdx.x;
  const int4 h4 = *(const int4*)(idx + (size_t)token * S_SP);
  const int h[4] = {h4.x, h4.y, h4.z, h4.w};
  const int d4 = tid * 4;
  const float4 xv = *(const float4*)(x + (size_t)token * D_DIM + d4);
  float p[4];
#pragma unroll
  for (int s2 = 0; s2 < 4; ++s2) {
    const float4 wv = *(const float4*)(W1 + (size_t)h[s2] * D_DIM + d4);
    p[s2] = xv.x * wv.x + xv.y * wv.y + xv.z * wv.z + xv.w * wv.w;
  }
#pragma unroll
  for (int s2 = 0; s2 < 4; ++s2) {
    float v = p[s2];
#pragma unroll
    for (int o = 32; o > 0; o >>= 1) v += __shfl_down(v, o);
    if ((tid & 63) == 0) red[tid >> 6][s2] = v;
  }
  __syncthreads();
  if (tid < 4) {
    const float tot = red[0][tid] + red[1][tid] + red[2][tid] + red[3][tid];
    const int hh = (tid == 0) ? h4.x : (tid == 1) ? h4.y : (tid == 2) ? h4.z : h4.w;
    const float v = tot + b1[hh];
    hv[tid] = v > 0.f ? v : 0.f;
  }
  __syncthreads();
  const float h0 = hv[0], h1 = hv[1], h2 = hv[2], h3 = hv[3];
  float4 o4 = *(const float4*)(b2 + d4);
  const float4 w0 = *(const float4*)(W2T + (size_t)h[0] * D_DIM + d4);
  const float4 w1 = *(const float4*)(W2T + (size_t)h[1] * D_DIM + d4);
  const float4 w2 = *(const float4*)(W2T + (size_t)h[2] * D_DIM + d4);
  const float4 w3 = *(const float4*)(W2T + (size_t)h[3] * D_DIM + d4);
  o4.x += h0 * w0.x + h1 * w1.x + h2 * w2.x + h3 * w3.x;
  o4.y += h0 * w0.y + h1 * w1.y + h2 * w2.y + h3 * w3.y;
  o4.z += h0 * w0.z + h1 * w1.z + h2 * w2.z + h3 * w3.z;
  o4.w += h0 * w0.w + h1 * w1.w + h2 * w2.w + h3 * w3.w;
  *(float4*)(out + (size_t)token * D_DIM + d4) = o4;
}

extern "C" void kernel_launch(void* const* d_in, const int* in_sizes, int n_in,
                              void* d_out, int out_size, void* d_ws, size_t ws_size,
                              hipStream_t stream) {
  const float* x      = (const float*)d_in[0];
  const float* W1     = (const float*)d_in[1];
  const float* b1     = (const float*)d_in[2];
  const float* W2     = (const float*)d_in[3];
  const float* b2     = (const float*)d_in[4];
  const float* Wc1    = (const float*)d_in[5];
  const float* bc1    = (const float*)d_in[6];
  const float* Wc2    = (const float*)d_in[7];
  const float* bc2    = (const float*)d_in[8];
  const float* gumbel = (const float*)d_in[9];
  float* out = (float*)d_out;

  char* ws = (char*)d_ws;
  float* W2T = (float*)ws;                                           // 16.78 MB
  float* ch  = (float*)(ws + (size_t)H_DIM * D_DIM * 4);             //  2.10 MB
  int*   idx = (int*)(ws + (size_t)H_DIM * D_DIM * 4
                         + (size_t)NTOK * R_DIM * 4);                //  0.13 MB

  hipLaunchKernelGGL(k_transpose, dim3(H_DIM / 64, D_DIM / 64), dim3(256), 0, stream,
                     W2, W2T);
  hipLaunchKernelGGL(k_ctrl, dim3(NTOK / K1_TOK), dim3(256), 0, stream,
                     x, Wc1, bc1, ch);
  hipLaunchKernelGGL(k_gate, dim3(NTOK / K2_TOK, S_SP), dim3(256), 0, stream,
                     ch, Wc2, bc2, gumbel, idx);
  hipLaunchKernelGGL(k_ffn, dim3(NTOK), dim3(256), 0, stream,
                     x, W1, b1, W2T, b2, idx, out);
}

// Round 3
// 291.171 us; speedup vs baseline: 9.8939x; 7.3940x over previous
//
#include <hip/hip_runtime.h>
#include <math.h>

#define D_DIM 1024
#define H_DIM 4096
#define R_DIM 64
#define S_SP  4
#define NTOK  8192
#define CHUNK 1024   // H/S

// ---------------- K0: transpose W2 (D,H) -> W2T (H,D) ----------------
__global__ __launch_bounds__(256) void k_transpose(const float* __restrict__ W2,
                                                   float* __restrict__ W2T) {
  __shared__ float tile[64][65];
  const int hb = blockIdx.x * 64, db = blockIdx.y * 64;
  const int tx = threadIdx.x & 63, ty = threadIdx.x >> 6;
#pragma unroll
  for (int r = 0; r < 16; ++r) {
    const int d = ty * 16 + r;
    tile[tx][d] = W2[(size_t)(db + d) * H_DIM + hb + tx];
  }
  __syncthreads();
#pragma unroll
  for (int r = 0; r < 16; ++r) {
    const int h = ty * 16 + r;
    W2T[(size_t)(hb + h) * D_DIM + db + tx] = tile[h][tx];
  }
}

// ---------------- K1: ch = relu(x @ Wc1^T + bc1)  (8192x64, K=1024) ----
#define K1_TOK 16
__global__ __launch_bounds__(256, 4) void k_ctrl(const float* __restrict__ x,
                                                 const float* __restrict__ Wc1,
                                                 const float* __restrict__ bc1,
                                                 float* __restrict__ ch) {
  __shared__ float xs[K1_TOK * 64];
  const int tid = threadIdx.x;
  const int tok0 = blockIdx.x * K1_TOK;
  const int r = tid & 63;   // output column r (R=64)
  const int g = tid >> 6;   // token group 0..3 (4 tokens each)
  float acc[4] = {0.f, 0.f, 0.f, 0.f};
#pragma unroll 1
  for (int kt = 0; kt < D_DIM; kt += 64) {
    __syncthreads();
    {
      const int tk = tid >> 4, kk = (tid & 15) * 4;
      *(float4*)(xs + tk * 64 + kk) =
          *(const float4*)(x + (size_t)(tok0 + tk) * D_DIM + kt + kk);
    }
    __syncthreads();
    // 16-float chunks; kk loop NOT unrolled -> bounded live set, no spill
#pragma unroll 1
    for (int kk = 0; kk < 4; ++kk) {
      const float4 w0 = *(const float4*)(Wc1 + (size_t)r * D_DIM + kt + kk * 16 + 0);
      const float4 w1 = *(const float4*)(Wc1 + (size_t)r * D_DIM + kt + kk * 16 + 4);
      const float4 w2 = *(const float4*)(Wc1 + (size_t)r * D_DIM + kt + kk * 16 + 8);
      const float4 w3 = *(const float4*)(Wc1 + (size_t)r * D_DIM + kt + kk * 16 + 12);
#pragma unroll
      for (int t = 0; t < 4; ++t) {
        const float* cp = xs + (g * 4 + t) * 64 + kk * 16;
        const float4 c0 = *(const float4*)(cp + 0);
        const float4 c1 = *(const float4*)(cp + 4);
        const float4 c2 = *(const float4*)(cp + 8);
        const float4 c3 = *(const float4*)(cp + 12);
        float a = acc[t];
        a = fmaf(c0.x, w0.x, a); a = fmaf(c0.y, w0.y, a);
        a = fmaf(c0.z, w0.z, a); a = fmaf(c0.w, w0.w, a);
        a = fmaf(c1.x, w1.x, a); a = fmaf(c1.y, w1.y, a);
        a = fmaf(c1.z, w1.z, a); a = fmaf(c1.w, w1.w, a);
        a = fmaf(c2.x, w2.x, a); a = fmaf(c2.y, w2.y, a);
        a = fmaf(c2.z, w2.z, a); a = fmaf(c2.w, w2.w, a);
        a = fmaf(c3.x, w3.x, a); a = fmaf(c3.y, w3.y, a);
        a = fmaf(c3.z, w3.z, a); a = fmaf(c3.w, w3.w, a);
        acc[t] = a;
      }
    }
  }
#pragma unroll
  for (int t = 0; t < 4; ++t) {
    const float v = acc[t] + bc1[r];
    ch[(size_t)(tok0 + g * 4 + t) * R_DIM + r] = v > 0.f ? v : 0.f;
  }
}

// ------- K2: logits = ch @ Wc2^T + bc2 (+gumbel), per-chunk argmax ------
// grid = (NTOK/K2_TOK, S). Thread owns h = hi*256+tid; persistent acc[16];
// kk loop NOT unrolled + VGPR cap 128 via launch_bounds -> no scratch spill.
#define K2_TOK 16
__global__ __launch_bounds__(256, 4) void k_gate(const float* __restrict__ ch,
                                                 const float* __restrict__ Wc2,
                                                 const float* __restrict__ bc2,
                                                 const float* __restrict__ gumbel,
                                                 int* __restrict__ idx) {
  __shared__ float chs[K2_TOK * 64];
  __shared__ float redv[4][K2_TOK];
  __shared__ int   redi[4][K2_TOK];
  const int tid = threadIdx.x;
  const int tok0 = blockIdx.x * K2_TOK;
  const int s = blockIdx.y;
  {
    const int tk = tid >> 4, kk = (tid & 15) * 4;
    *(float4*)(chs + tk * 64 + kk) =
        *(const float4*)(ch + (size_t)(tok0 + tk) * R_DIM + kk);
  }
  __syncthreads();
  float bv[K2_TOK];
  int   bi[K2_TOK];
#pragma unroll
  for (int t = 0; t < K2_TOK; ++t) { bv[t] = -INFINITY; bi[t] = 0; }
#pragma unroll 1
  for (int hi = 0; hi < 4; ++hi) {
    const int hloc = hi * 256 + tid;              // h within chunk, 0..1023
    const float* wrow = Wc2 + (size_t)(s * CHUNK + hloc) * R_DIM;
    float acc[K2_TOK];
#pragma unroll
    for (int t = 0; t < K2_TOK; ++t) acc[t] = 0.f;
#pragma unroll 1
    for (int kk = 0; kk < 4; ++kk) {
      const float4 w0 = *(const float4*)(wrow + kk * 16 + 0);
      const float4 w1 = *(const float4*)(wrow + kk * 16 + 4);
      const float4 w2 = *(const float4*)(wrow + kk * 16 + 8);
      const float4 w3 = *(const float4*)(wrow + kk * 16 + 12);
#pragma unroll
      for (int t = 0; t < K2_TOK; ++t) {
        const float* cp = chs + t * 64 + kk * 16;
        const float4 c0 = *(const float4*)(cp + 0);
        const float4 c1 = *(const float4*)(cp + 4);
        const float4 c2 = *(const float4*)(cp + 8);
        const float4 c3 = *(const float4*)(cp + 12);
        float a = acc[t];
        a = fmaf(c0.x, w0.x, a); a = fmaf(c0.y, w0.y, a);
        a = fmaf(c0.z, w0.z, a); a = fmaf(c0.w, w0.w, a);
        a = fmaf(c1.x, w1.x, a); a = fmaf(c1.y, w1.y, a);
        a = fmaf(c1.z, w1.z, a); a = fmaf(c1.w, w1.w, a);
        a = fmaf(c2.x, w2.x, a); a = fmaf(c2.y, w2.y, a);
        a = fmaf(c2.z, w2.z, a); a = fmaf(c2.w, w2.w, a);
        a = fmaf(c3.x, w3.x, a); a = fmaf(c3.y, w3.y, a);
        a = fmaf(c3.z, w3.z, a); a = fmaf(c3.w, w3.w, a);
        acc[t] = a;
      }
    }
    const float bias = bc2[s * CHUNK + hloc];
    const float* gp = gumbel + ((size_t)tok0 * 4 + s) * CHUNK + hloc;
#pragma unroll
    for (int t = 0; t < K2_TOK; ++t) {
      const float val = acc[t] + bias + gp[(size_t)t * 4 * CHUNK];
      if (val > bv[t] || (val == bv[t] && hloc < bi[t])) { bv[t] = val; bi[t] = hloc; }
    }
  }
  // argmax reduce: wave shuffle, then cross-wave via LDS
#pragma unroll
  for (int t = 0; t < K2_TOK; ++t) {
    float v = bv[t];
    int ii = bi[t];
#pragma unroll
    for (int o = 32; o > 0; o >>= 1) {
      const float ov = __shfl_down(v, o);
      const int   oi = __shfl_down(ii, o);
      if (ov > v || (ov == v && oi < ii)) { v = ov; ii = oi; }
    }
    if ((tid & 63) == 0) { redv[tid >> 6][t] = v; redi[tid >> 6][t] = ii; }
  }
  __syncthreads();
  if (tid < K2_TOK) {
    float v = redv[0][tid];
    int ii = redi[0][tid];
#pragma unroll
    for (int wv = 1; wv < 4; ++wv) {
      const float ov = redv[wv][tid];
      const int   oi = redi[wv][tid];
      if (ov > v || (ov == v && oi < ii)) { v = ov; ii = oi; }
    }
    idx[(size_t)(tok0 + tid) * S_SP + s] = s * CHUNK + ii;
  }
}

// ------- K3: per-token sparse FFN: 4 dots with W1 rows, combine W2T rows ---
__global__ __launch_bounds__(256) void k_ffn(const float* __restrict__ x,
                                             const float* __restrict__ W1,
                                             const float* __restrict__ b1,
                                             const float* __restrict__ W2T,
                                             const float* __restrict__ b2,
                                             const int* __restrict__ idx,
                                             float* __restrict__ out) {
  __shared__ float red[4][4];
  __shared__ float hv[4];
  const int token = blockIdx.x;
  const int tid = threadIdx.x;
  const int4 h4 = *(const int4*)(idx + (size_t)token * S_SP);
  const int h[4] = {h4.x, h4.y, h4.z, h4.w};
  const int d4 = tid * 4;
  const float4 xv = *(const float4*)(x + (size_t)token * D_DIM + d4);
  float p[4];
#pragma unroll
  for (int s2 = 0; s2 < 4; ++s2) {
    const float4 wv = *(const float4*)(W1 + (size_t)h[s2] * D_DIM + d4);
    p[s2] = xv.x * wv.x + xv.y * wv.y + xv.z * wv.z + xv.w * wv.w;
  }
#pragma unroll
  for (int s2 = 0; s2 < 4; ++s2) {
    float v = p[s2];
#pragma unroll
    for (int o = 32; o > 0; o >>= 1) v += __shfl_down(v, o);
    if ((tid & 63) == 0) red[tid >> 6][s2] = v;
  }
  __syncthreads();
  if (tid < 4) {
    const float tot = red[0][tid] + red[1][tid] + red[2][tid] + red[3][tid];
    const int hh = (tid == 0) ? h4.x : (tid == 1) ? h4.y : (tid == 2) ? h4.z : h4.w;
    const float v = tot + b1[hh];
    hv[tid] = v > 0.f ? v : 0.f;
  }
  __syncthreads();
  const float h0 = hv[0], h1 = hv[1], h2 = hv[2], h3 = hv[3];
  float4 o4 = *(const float4*)(b2 + d4);
  const float4 w0 = *(const float4*)(W2T + (size_t)h[0] * D_DIM + d4);
  const float4 w1 = *(const float4*)(W2T + (size_t)h[1] * D_DIM + d4);
  const float4 w2 = *(const float4*)(W2T + (size_t)h[2] * D_DIM + d4);
  const float4 w3 = *(const float4*)(W2T + (size_t)h[3] * D_DIM + d4);
  o4.x += h0 * w0.x + h1 * w1.x + h2 * w2.x + h3 * w3.x;
  o4.y += h0 * w0.y + h1 * w1.y + h2 * w2.y + h3 * w3.y;
  o4.z += h0 * w0.z + h1 * w1.z + h2 * w2.z + h3 * w3.z;
  o4.w += h0 * w0.w + h1 * w1.w + h2 * w2.w + h3 * w3.w;
  *(float4*)(out + (size_t)token * D_DIM + d4) = o4;
}

extern "C" void kernel_launch(void* const* d_in, const int* in_sizes, int n_in,
                              void* d_out, int out_size, void* d_ws, size_t ws_size,
                              hipStream_t stream) {
  const float* x      = (const float*)d_in[0];
  const float* W1     = (const float*)d_in[1];
  const float* b1     = (const float*)d_in[2];
  const float* W2     = (const float*)d_in[3];
  const float* b2     = (const float*)d_in[4];
  const float* Wc1    = (const float*)d_in[5];
  const float* bc1    = (const float*)d_in[6];
  const float* Wc2    = (const float*)d_in[7];
  const float* bc2    = (const float*)d_in[8];
  const float* gumbel = (const float*)d_in[9];
  float* out = (float*)d_out;

  char* ws = (char*)d_ws;
  float* W2T = (float*)ws;                                           // 16.78 MB
  float* ch  = (float*)(ws + (size_t)H_DIM * D_DIM * 4);             //  2.10 MB
  int*   idx = (int*)(ws + (size_t)H_DIM * D_DIM * 4
                         + (size_t)NTOK * R_DIM * 4);                //  0.13 MB

  hipLaunchKernelGGL(k_transpose, dim3(H_DIM / 64, D_DIM / 64), dim3(256), 0, stream,
                     W2, W2T);
  hipLaunchKernelGGL(k_ctrl, dim3(NTOK / K1_TOK), dim3(256), 0, stream,
                     x, Wc1, bc1, ch);
  hipLaunchKernelGGL(k_gate, dim3(NTOK / K2_TOK, S_SP), dim3(256), 0, stream,
                     ch, Wc2, bc2, gumbel, idx);
  hipLaunchKernelGGL(k_ffn, dim3(NTOK), dim3(256), 0, stream,
                     x, W1, b1, W2T, b2, idx, out);
}